// Round 1
// baseline (669.955 us; speedup 1.0000x reference)
//
#include <hip/hip_runtime.h>
#include <hip/hip_bf16.h>

#define ALPHA_MARGIN 1.0f

// One wave (64 lanes) per pair. Each pair's row is 256 fp32 = 64 float4:
// lane i loads float4 #i -> lanes 0..31 hold e_a, lanes 32..63 hold e_b.
// __shfl_xor(.,32) swaps halves so every lane has its partner's 4 elems.
// Each lane's partial (a-b)^2 sum is symmetric across halves, so a
// butterfly reduce with masks 16..1 yields dist2 in every lane.
__global__ __launch_bounds__(256) void closs_kernel(
        const float4* __restrict__ X4,
        const int*    __restrict__ y,
        float*        __restrict__ out,
        int n_pairs) {
    int wave = (int)((blockIdx.x * blockDim.x + threadIdx.x) >> 6);
    int lane = threadIdx.x & 63;
    if (wave >= n_pairs) return;

    float4 v = X4[(size_t)wave * 64 + lane];

    float ox = __shfl_xor(v.x, 32);
    float oy = __shfl_xor(v.y, 32);
    float oz = __shfl_xor(v.z, 32);
    float ow = __shfl_xor(v.w, 32);

    float dx = v.x - ox;
    float dy = v.y - oy;
    float dz = v.z - oz;
    float dw = v.w - ow;
    float s = dx * dx + dy * dy + dz * dz + dw * dw;

    // reduce within each 32-lane half (halves are identical after xor-32)
    #pragma unroll
    for (int m = 16; m >= 1; m >>= 1)
        s += __shfl_xor(s, m);

    if (lane == 0) {
        int adj = y[wave];
        float loss;
        if (adj == 1)      loss = s;
        else if (adj == 0) loss = fmaxf(ALPHA_MARGIN - s, 0.0f);
        else               loss = 0.0f;
        out[wave] = loss;
    }
}

extern "C" void kernel_launch(void* const* d_in, const int* in_sizes, int n_in,
                              void* d_out, int out_size, void* d_ws, size_t ws_size,
                              hipStream_t stream) {
    const float* X = (const float*)d_in[0];
    const int*   y = (const int*)d_in[1];
    float* out = (float*)d_out;

    int n_pairs = in_sizes[1];           // B * N * N = 524288
    // 1 wave per pair, 4 waves per 256-thread block
    int blocks = (n_pairs + 3) / 4;

    closs_kernel<<<blocks, 256, 0, stream>>>((const float4*)X, y, out, n_pairs);
}